// Round 1
// baseline (648.193 us; speedup 1.0000x reference)
//
#include <hip/hip_runtime.h>
#include <hip/hip_bf16.h>

// Problem constants (from reference): N=1e6 nodes, V=6e5 var nodes, H=128.
constexpr int H = 128;
constexpr int V = 600000;
constexpr int NTOT = 1000000;

// Precompute u[h] = sum_k W_llr[k] * W_gate[(H+k)*H + h]
//            c[h] = sum_k b_llr[k] * W_gate[(H+k)*H + h] + b_gate[h]
// so logits[i][h] = var_f[i] . W1[:,h] + llr_i * u[h] + c[h]
__global__ void precompute_uc_kernel(const float* __restrict__ W_llr,
                                     const float* __restrict__ b_llr,
                                     const float* __restrict__ W_gate,
                                     const float* __restrict__ b_gate,
                                     float* __restrict__ uc) {
    int h = threadIdx.x;  // 128 threads
    float u = 0.0f, c = 0.0f;
    for (int k = 0; k < H; ++k) {
        float w2 = W_gate[(size_t)(H + k) * H + h];
        u += W_llr[k] * w2;
        c += b_llr[k] * w2;
    }
    uc[h] = u;
    uc[H + h] = c + b_gate[h];
}

// One thread = one row. W1 (= first H rows of W_gate) is read with
// wave-uniform indices -> scalar loads (s_load), FMAs are v_fmac v,s,v.
// acc[32] per column-group (4 groups of 32 columns), static indexing only.
__global__ __launch_bounds__(256) void fused_residual_llr_kernel(
    const float* __restrict__ nf,      // node_features [N][H]
    const float* __restrict__ llr,     // original_llr [V]
    const float* __restrict__ W_llr,   // [H]
    const float* __restrict__ b_llr,   // [H]
    const float* __restrict__ W_gate,  // [2H][H]
    const float* __restrict__ uc,      // [2H]: u then c
    float* __restrict__ out,           // [N][H]
    int nComputeBlocks) {
    int b = blockIdx.x;

    if (b >= nComputeBlocks) {
        // ---- copy region: rows V..N, coalesced float4 grid-stride ----
        size_t base = (size_t)V * H;
        size_t n4 = ((size_t)(NTOT - V) * H) / 4;
        const float4* src = reinterpret_cast<const float4*>(nf + base);
        float4* dst = reinterpret_cast<float4*>(out + base);
        size_t i = (size_t)(b - nComputeBlocks) * blockDim.x + threadIdx.x;
        size_t stride = (size_t)(gridDim.x - nComputeBlocks) * blockDim.x;
        for (; i < n4; i += stride) dst[i] = src[i];
        return;
    }

    // ---- compute region: one row per thread ----
    int r = b * 256 + threadIdx.x;
    if (r >= V) return;

    const float4* frow = reinterpret_cast<const float4*>(nf + (size_t)r * H);
    float4* orow = reinterpret_cast<float4*>(out + (size_t)r * H);
    float l = llr[r];

#pragma unroll
    for (int cg = 0; cg < 4; ++cg) {
        float acc[32];
#pragma unroll
        for (int c = 0; c < 32; ++c)
            acc[c] = fmaf(l, uc[cg * 32 + c], uc[H + cg * 32 + c]);

#pragma unroll 1
        for (int kt = 0; kt < 16; ++kt) {  // k in tiles of 8
            float4 fa = frow[kt * 2];
            float4 fb = frow[kt * 2 + 1];
            float f8[8] = {fa.x, fa.y, fa.z, fa.w, fb.x, fb.y, fb.z, fb.w};
#pragma unroll
            for (int j = 0; j < 8; ++j) {
                const float* wrow = W_gate + (size_t)(kt * 8 + j) * H + cg * 32;
#pragma unroll
                for (int c = 0; c < 32; ++c)
                    acc[c] = fmaf(f8[j], wrow[c], acc[c]);
            }
        }

        // epilogue: sigmoid gate, blend, store 32 cols
#pragma unroll
        for (int cq = 0; cq < 8; ++cq) {
            float4 vf = frow[cg * 8 + cq];
            float vfa[4] = {vf.x, vf.y, vf.z, vf.w};
            float oa[4];
#pragma unroll
            for (int e = 0; e < 4; ++e) {
                int h = cg * 32 + cq * 4 + e;
                float x = acc[cq * 4 + e];
                float g = 1.0f / (1.0f + __expf(-x));
                float lf = fmaf(l, W_llr[h], b_llr[h]);
                oa[e] = g * lf + (1.0f - g) * vfa[e];
            }
            float4 o = {oa[0], oa[1], oa[2], oa[3]};
            orow[cg * 8 + cq] = o;
        }
    }
}

extern "C" void kernel_launch(void* const* d_in, const int* in_sizes, int n_in,
                              void* d_out, int out_size, void* d_ws, size_t ws_size,
                              hipStream_t stream) {
    const float* nf     = (const float*)d_in[0];  // node_features [N*H]
    const float* llr    = (const float*)d_in[1];  // original_llr [V]
    const float* W_llr  = (const float*)d_in[2];  // [H]
    const float* b_llr  = (const float*)d_in[3];  // [H]
    const float* W_gate = (const float*)d_in[4];  // [2H*H]
    const float* b_gate = (const float*)d_in[5];  // [H]
    // d_in[6] = var_node_mask (unused by the reference computation)
    float* out = (float*)d_out;
    float* uc  = (float*)d_ws;  // 256 floats

    precompute_uc_kernel<<<1, 128, 0, stream>>>(W_llr, b_llr, W_gate, b_gate, uc);

    int nCompute = (V + 255) / 256;  // 2344
    int nCopy = 1536;
    fused_residual_llr_kernel<<<nCompute + nCopy, 256, 0, stream>>>(
        nf, llr, W_llr, b_llr, W_gate, uc, out, nCompute);
}